// Round 4
// baseline (402.220 us; speedup 1.0000x reference)
//
#include <hip/hip_runtime.h>

#define N_NODES 100000
#define K_EIG   256
#define C_CH    128
#define NCHUNK  390              // chunks 0..388: 256 rows (8 slabs); chunk 389: 416 rows (13 slabs)
#define PART_TILE (256*128)      // fp32 per partial tile; 390 tiles = 51.118 MB <= d_out (51.2 MB)
#define G2_BLOCKS 782            // ceil(N_NODES / 128)

typedef __attribute__((ext_vector_type(8))) short  short8;
typedef __attribute__((ext_vector_type(4))) float  float4v;

// fp32 -> bf16 bits with round-to-nearest-even
__device__ __forceinline__ unsigned int bf16_bits(float f) {
  union { float f; unsigned int u; } v; v.f = f;
  unsigned int r = v.u + 0x7fffu + ((v.u >> 16) & 1u);
  return r >> 16;
}

// ---------------------------------------------------------------------------
// GEMM1: partial[chunk][k][c] = sum_{n in chunk} evecs[n][k] * x[n][c]
// LDS-free, barrier-free. MFMA fragments loaded straight from global:
// per 32-row slab, lane (q,lc) reads A = evecs[r0+j][m-col] and
// B = x[r0+j][c-col] as dwords -- 16 consecutive lanes = 64B segments,
// 4 rows per instruction, fully coalesced, every byte used.
// Wave w owns eigen rows [w*64, w*64+64) (full K=256 per block => x read once).
// ---------------------------------------------------------------------------
__global__ __launch_bounds__(256, 2) void gemm1_kernel(
    const float* __restrict__ x, const float* __restrict__ evecs,
    float* __restrict__ partial) {
  const int tid = threadIdx.x;
  const int chunk = blockIdx.x;
  const int w  = tid >> 6;
  const int l  = tid & 63;
  const int q  = l >> 4;
  const int lc = l & 15;

  const int base   = chunk * 256;
  const int nslab  = (chunk == NCHUNK - 1) ? 13 : 8;

  float4v acc[4][8];
#pragma unroll
  for (int a = 0; a < 4; a++)
#pragma unroll
    for (int b = 0; b < 8; b++) acc[a][b] = (float4v)0.0f;

  for (int s = 0; s < nslab; s++) {
    const int r0 = base + s * 32 + q * 8;            // this quad's 8 reduction rows
    const float* er = evecs + (size_t)r0 * K_EIG + w * 64 + lc;
    const float* xr = x     + (size_t)r0 * C_CH  + lc;

    // A fragments: af[mt][j] = evecs[r0+j][w*64 + mt*16 + lc]
    float av[4][8];
#pragma unroll
    for (int mt = 0; mt < 4; mt++)
#pragma unroll
      for (int j = 0; j < 8; j++) av[mt][j] = er[(size_t)j * K_EIG + mt * 16];
    short8 af[4];
#pragma unroll
    for (int mt = 0; mt < 4; mt++)
#pragma unroll
      for (int j = 0; j < 8; j++) af[mt][j] = (short)bf16_bits(av[mt][j]);

    // B fragments, first half (ct 0..3), then MFMA; then second half.
#pragma unroll
    for (int h = 0; h < 2; h++) {
      float bv[4][8];
#pragma unroll
      for (int ci = 0; ci < 4; ci++)
#pragma unroll
        for (int j = 0; j < 8; j++)
          bv[ci][j] = xr[(size_t)j * C_CH + (h * 4 + ci) * 16];
      short8 bf[4];
#pragma unroll
      for (int ci = 0; ci < 4; ci++)
#pragma unroll
        for (int j = 0; j < 8; j++) bf[ci][j] = (short)bf16_bits(bv[ci][j]);
#pragma unroll
      for (int ci = 0; ci < 4; ci++)
#pragma unroll
        for (int mt = 0; mt < 4; mt++)
          acc[mt][h * 4 + ci] = __builtin_amdgcn_mfma_f32_16x16x32_bf16(
              af[mt], bf[ci], acc[mt][h * 4 + ci], 0, 0, 0);
    }
  }

  // C/D layout: col = lane&15, row = (lane>>4)*4 + reg
  float* pb = partial + (size_t)chunk * PART_TILE;
#pragma unroll
  for (int mt = 0; mt < 4; mt++)
#pragma unroll
    for (int ct = 0; ct < 8; ct++)
#pragma unroll
      for (int r = 0; r < 4; r++) {
        const int m = w * 64 + mt * 16 + q * 4 + r;
        const int c = ct * 16 + lc;
        pb[m * 128 + c] = acc[mt][ct][r];
      }
}

// ---------------------------------------------------------------------------
// Reduce partials over 390 chunks (float4 strided reads, 8-way split),
// apply exp(-lambda*t), emit bf16 s pre-shuffled into MFMA B-fragment order:
//   idx = (((k/32)*8 + c/16)*64 + ((k%32)/8)*16 + (c%16))*8 + (k%8)
// ---------------------------------------------------------------------------
__global__ __launch_bounds__(256) void reduce_kernel(
    const float* __restrict__ partial, const float* __restrict__ evals,
    const float* __restrict__ dt, unsigned short* __restrict__ s_frag) {
  __shared__ float4v red[256];
  const int t = threadIdx.x;
  const int g = blockIdx.x * 32 + (t & 31);     // float4-group 0..8191 within tile
  const int p = t >> 5;                          // 0..7 chunk slice
  const float4v* basep = (const float4v*)partial + g;

  float4v a0 = (float4v)0.f, a1 = (float4v)0.f, a2 = (float4v)0.f, a3 = (float4v)0.f;
  int ch = p;
  for (; ch + 24 < NCHUNK; ch += 32) {
    a0 += basep[(size_t)(ch     ) * (PART_TILE / 4)];
    a1 += basep[(size_t)(ch +  8) * (PART_TILE / 4)];
    a2 += basep[(size_t)(ch + 16) * (PART_TILE / 4)];
    a3 += basep[(size_t)(ch + 24) * (PART_TILE / 4)];
  }
  for (; ch < NCHUNK; ch += 8) a0 += basep[(size_t)ch * (PART_TILE / 4)];
  red[t] = (a0 + a1) + (a2 + a3);
  __syncthreads();

  if (t < 32) {
    float4v tot = red[t];
#pragma unroll
    for (int pp = 1; pp < 8; pp++) tot += red[pp * 32 + t];
    const int gg = blockIdx.x * 32 + t;
    const int k  = gg >> 5;                      // eigen index 0..255
    const int c0 = (gg & 31) * 4;                // channel base
    const float tv   = fmaxf(dt[0], 1e-8f);
    const float coef = expf(-evals[k] * tv);
#pragma unroll
    for (int e = 0; e < 4; e++) {
      const int c = c0 + e;
      const float v = tot[e] * coef;
      const int idx = ((((k >> 5) * 8 + (c >> 4)) * 64) + ((k & 31) >> 3) * 16 + (c & 15)) * 8 + (k & 7);
      s_frag[idx] = (unsigned short)bf16_bits(v);
    }
  }
}

// ---------------------------------------------------------------------------
// GEMM2: out[n][c] = sum_k evecs[n][k] * s[k][c]
// No LDS: B-fragments stream from the fragment-ordered 64KB s buffer
// (L2-resident, lane-contiguous 16B reads); A rows straight from global
// with explicit ks+1 register prefetch.
// ---------------------------------------------------------------------------
__global__ __launch_bounds__(256, 3) void gemm2_kernel(
    const float* __restrict__ evecs, const unsigned short* __restrict__ s_frag,
    float* __restrict__ out) {
  const int tid = threadIdx.x;
  const int w  = tid >> 6, l = tid & 63, q = l >> 4, lc = l & 15;
  const int rowbase = blockIdx.x * 128 + w * 32;

  int n0 = rowbase + lc;        n0 = (n0 < N_NODES) ? n0 : (N_NODES - 1);
  int n1 = rowbase + 16 + lc;   n1 = (n1 < N_NODES) ? n1 : (N_NODES - 1);
  const float* row0 = evecs + (size_t)n0 * K_EIG + q * 8;
  const float* row1 = evecs + (size_t)n1 * K_EIG + q * 8;

  float4v acc[2][8];
#pragma unroll
  for (int a = 0; a < 2; a++)
#pragma unroll
    for (int b = 0; b < 8; b++) acc[a][b] = (float4v)0.0f;

  float4v c00 = *(const float4v*)(row0);
  float4v c01 = *(const float4v*)(row0 + 4);
  float4v c10 = *(const float4v*)(row1);
  float4v c11 = *(const float4v*)(row1 + 4);

#pragma unroll
  for (int ks = 0; ks < 8; ks++) {
    float4v nx00, nx01, nx10, nx11;
    if (ks < 7) {
      nx00 = *(const float4v*)(row0 + (ks + 1) * 32);
      nx01 = *(const float4v*)(row0 + (ks + 1) * 32 + 4);
      nx10 = *(const float4v*)(row1 + (ks + 1) * 32);
      nx11 = *(const float4v*)(row1 + (ks + 1) * 32 + 4);
    }
    short8 a0, a1;
    a0[0] = (short)bf16_bits(c00.x); a0[1] = (short)bf16_bits(c00.y);
    a0[2] = (short)bf16_bits(c00.z); a0[3] = (short)bf16_bits(c00.w);
    a0[4] = (short)bf16_bits(c01.x); a0[5] = (short)bf16_bits(c01.y);
    a0[6] = (short)bf16_bits(c01.z); a0[7] = (short)bf16_bits(c01.w);
    a1[0] = (short)bf16_bits(c10.x); a1[1] = (short)bf16_bits(c10.y);
    a1[2] = (short)bf16_bits(c10.z); a1[3] = (short)bf16_bits(c10.w);
    a1[4] = (short)bf16_bits(c11.x); a1[5] = (short)bf16_bits(c11.y);
    a1[6] = (short)bf16_bits(c11.z); a1[7] = (short)bf16_bits(c11.w);
#pragma unroll
    for (int ct = 0; ct < 8; ct++) {
      const short8 b = *(const short8*)&s_frag[(size_t)((ks * 8 + ct) * 64 + l) * 8];
      acc[0][ct] = __builtin_amdgcn_mfma_f32_16x16x32_bf16(a0, b, acc[0][ct], 0, 0, 0);
      acc[1][ct] = __builtin_amdgcn_mfma_f32_16x16x32_bf16(a1, b, acc[1][ct], 0, 0, 0);
    }
    c00 = nx00; c01 = nx01; c10 = nx10; c11 = nx11;
  }

#pragma unroll
  for (int rt = 0; rt < 2; rt++)
#pragma unroll
    for (int ct = 0; ct < 8; ct++)
#pragma unroll
      for (int r = 0; r < 4; r++) {
        const int n = rowbase + rt * 16 + q * 4 + r;
        if (n < N_NODES) out[(size_t)n * C_CH + ct * 16 + lc] = acc[rt][ct][r];
      }
}

// ---------------------------------------------------------------------------
extern "C" void kernel_launch(void* const* d_in, const int* in_sizes, int n_in,
                              void* d_out, int out_size, void* d_ws, size_t ws_size,
                              hipStream_t stream) {
  const float* x     = (const float*)d_in[0];   // [N, C]
  const float* evals = (const float*)d_in[1];   // [K]
  const float* evecs = (const float*)d_in[2];   // [N, K]
  const float* dt    = (const float*)d_in[3];   // [1]
  float* out = (float*)d_out;                   // [N, C] fp32

  // d_out doubles as split-K partial scratch: 390 tiles * 128KB = 51.118 MB.
  float* partial = out;
  unsigned short* s_frag = (unsigned short*)d_ws;  // 64 KB bf16, fragment-ordered

  gemm1_kernel<<<NCHUNK, 256, 0, stream>>>(x, evecs, partial);
  reduce_kernel<<<256, 256, 0, stream>>>(partial, evals, dt, s_frag);
  gemm2_kernel<<<G2_BLOCKS, 256, 0, stream>>>(evecs, s_frag, out);
}